// Round 3
// baseline (35033.160 us; speedup 1.0000x reference)
//
#include <hip/hip_runtime.h>
#include <stdint.h>

// Problem constants
#define HD       64
#define MM       256
#define BB       1024
#define LL       2048
#define NGROUP   16
#define WPG      64          // A-waves per slot group (1024/16)
#define SCALE_   0.125f
#define GATE_X4  10737418240ull   // 2560 * 2^20 * 4

// ---------------- workspace (d_ws) layout, bytes ----------------
#define WS_SLOTS 0           // 16*2048*u64 = 262144 (zeroed each launch)
#define WS_WPA   262144      // [32 kp][3 g][64 j] u32 bf16-pairs of w_ih r-cols (24576)
#define WS_WPB   286720      // [32 kp][3 g][64 j] u32 bf16-pairs of w_hh      (24576)
#define WS_G     311296      // [64 tok][96] u32 bf16 pairs: embed@Wx^T + b_ih (24576)
#define WS_HWT2  335872      // [32 hp][64 o] float2 head_w pairs over h       (16384)
#define WS_W2    352256      // [64][64] f32 wk^T@wq                           (16384)
#define WS_D     368640      // [64] f32 bk@wq
#define WS_E     368896      // [64] f32 bq@wk
#define WS_F     369152      // f32 bq.bk

// ---------------- main-phase LDS layout ----------------
#define LD_WPA   0           // 24576
#define LD_WPB   24576       // 24576
#define LD_G     49152       // 24576
#define LD_HWT2  73728       // 16384
#define LD_DYN   90112       // 4 b * 4096
#define DYN_STRIDE 4096
#define DY_GI    0           // 3*64 f32
#define DY_GH    768
#define DY_HNB   1536        // 64 f32
#define DY_NUM   1792        // 2*64 f32 (PV numerator halves)
#define DY_WEXP  2304        // 2*128 f32
#define DY_SMAX  3328        // 2 f32
#define DY_SEH   3336        // 2 f32

// ---------------- phase-0 overlay ----------------
#define P0_W2P   0           // 8192  bf16 pairs of W2 over h
#define P0_WVT2  8192        // 8192  bf16 pairs of wv^T over h2
#define P0_D     16384
#define P0_E     16640
#define P0_F     16896
#define P0_MC    17408       // + wv*16640 : [64][65] f32 memory chunk
#define MC_BYTES 16640

#define LDS_BYTES 150528

__device__ __forceinline__ unsigned bf16r(float x) {
  unsigned u = __float_as_uint(x);
  return (u + 0x7fffu + ((u >> 16) & 1u)) >> 16;
}
__device__ __forceinline__ unsigned pack2(float a, float b) {
  return bf16r(a) | (bf16r(b) << 16);
}
__device__ __forceinline__ float lo16(unsigned u) { return __uint_as_float(u << 16); }
__device__ __forceinline__ float hi16(unsigned u) { return __uint_as_float(u & 0xffff0000u); }

#define WAVE_FENCE() asm volatile("s_waitcnt lgkmcnt(0)" ::: "memory")

// Relaxed-only grid gate: value+count packed in one u64 per slot.
__device__ __forceinline__ bool poll_cond(const unsigned long long* slots, int t, int lane) {
  const unsigned long long* p = slots + (size_t)(lane & 15) * LL + t;
  unsigned long long v;
  for (;;) {
    v = __hip_atomic_load(p, __ATOMIC_RELAXED, __HIP_MEMORY_SCOPE_AGENT);
    if (__all((int)(v >> 48) == WPG)) break;
    __builtin_amdgcn_s_sleep(1);
  }
  unsigned long long s = v & 0xFFFFFFFFFFFFull;
#pragma unroll
  for (int off = 32; off; off >>= 1) s += __shfl_xor(s, off, 64);
  return s > GATE_X4;
}

// =====================================================================
// P1: one-time weight preprocessing into workspace
// =====================================================================
extern "C" __global__ void reactive_pre(
    const float* __restrict__ embed, const float* __restrict__ w_ih,
    const float* __restrict__ w_hh,  const float* __restrict__ b_ih,
    const float* __restrict__ wq,    const float* __restrict__ bq,
    const float* __restrict__ wk,    const float* __restrict__ bk,
    const float* __restrict__ head_w, unsigned char* __restrict__ ws)
{
  const int tid = threadIdx.x;  // 1024 threads, 1 block

  unsigned* wpa = (unsigned*)(ws + WS_WPA);
  unsigned* wpb = (unsigned*)(ws + WS_WPB);
  for (int i = tid; i < 6144; i += 1024) {
    int q = i / 192, rem = i % 192;      // [kp][g*64+j]
    int row = rem;                        // g*64+j in 0..191
    wpa[i] = pack2(w_ih[row * 128 + 64 + 2 * q], w_ih[row * 128 + 64 + 2 * q + 1]);
    wpb[i] = pack2(w_hh[row * 64 + 2 * q],       w_hh[row * 64 + 2 * q + 1]);
  }
  unsigned* gp = (unsigned*)(ws + WS_G);
  for (int i = tid; i < 64 * 96; i += 1024) {
    int v = i / 96, u = i % 96;
    int j0 = 2 * u, j1 = j0 + 1;
    float g0 = b_ih[j0], g1 = b_ih[j1];
    for (int h = 0; h < 64; ++h) {
      float ev = embed[v * 64 + h];
      g0 = fmaf(ev, w_ih[j0 * 128 + h], g0);
      g1 = fmaf(ev, w_ih[j1 * 128 + h], g1);
    }
    gp[i] = pack2(g0, g1);
  }
  float2* hwt2 = (float2*)(ws + WS_HWT2);
  for (int i = tid; i < 2048; i += 1024) {
    int hp = i >> 6, o = i & 63;
    hwt2[i] = make_float2(head_w[o * 64 + 2 * hp], head_w[o * 64 + 2 * hp + 1]);
  }
  float* w2 = (float*)(ws + WS_W2);
  for (int i = tid; i < 4096; i += 1024) {
    int h2 = i >> 6, h = i & 63;
    float a = 0.f;
    for (int o = 0; o < 64; ++o) a = fmaf(wk[o * 64 + h2], wq[o * 64 + h], a);
    w2[i] = a;
  }
  if (tid < 64) {
    float a = 0.f, b2 = 0.f;
    for (int o = 0; o < 64; ++o) a  = fmaf(bk[o], wq[o * 64 + tid], a);
    for (int o = 0; o < 64; ++o) b2 = fmaf(bq[o], wk[o * 64 + tid], b2);
    ((float*)(ws + WS_D))[tid] = a;
    ((float*)(ws + WS_E))[tid] = b2;
  }
  if (tid == 0) {
    float a = 0.f;
    for (int o = 0; o < 64; ++o) a = fmaf(bq[o], bk[o], a);
    *(float*)(ws + WS_F) = a;
  }
}

// =====================================================================
// Main persistent kernel: 256 blocks x 512 threads (8 waves = 4 b's x {A,B}).
// 2 waves/SIMD. Wave A: gi + entropy gate + post/poll. Wave B: gh.
// Attention split by m-halves; 2-way softmax exchange via LDS.
// =====================================================================
extern "C" __global__ void __launch_bounds__(512, 2)
reactive_main(const int* __restrict__ seq, const float* __restrict__ memory,
              const float* __restrict__ wvp, const float* __restrict__ bvp,
              const float* __restrict__ b_hh, const float* __restrict__ head_w,
              const float* __restrict__ head_b, unsigned char* __restrict__ ws,
              float* __restrict__ out)
{
  extern __shared__ __align__(16) unsigned char lds[];
  const int tid     = threadIdx.x;
  const int wv      = tid >> 6;
  const int lane    = tid & 63;
  const int half    = wv >> 2;       // 0 = A, 1 = B  (A on wv0-3 -> one A + one B per SIMD)
  const int b_local = wv & 3;
  const int b       = (int)blockIdx.x * 4 + b_local;
  const int grp     = b & (NGROUP - 1);
  const bool isA    = (half == 0);

  unsigned kp[2][32];   // K' bf16 pairs for m = half*128 + g*64 + lane
  unsigned vt[64];      // V bf16 pairs over this half's 128 m-rows
  float    cm[2];

  // ---------------- phase 0: per-(b,half) K', V^T, c into registers ----------------
  {
    unsigned* w2p  = (unsigned*)(lds + P0_W2P);
    unsigned* wvt2 = (unsigned*)(lds + P0_WVT2);
    float* pD = (float*)(lds + P0_D);
    float* pE = (float*)(lds + P0_E);
    float* pF = (float*)(lds + P0_F);
    const float* wsW2 = (const float*)(ws + WS_W2);
    for (int i = tid; i < 2048; i += 512) {
      int h2 = i >> 5, hp = i & 31;
      w2p[i] = pack2(wsW2[h2 * 64 + 2 * hp], wsW2[h2 * 64 + 2 * hp + 1]);
    }
    for (int i = tid; i < 2048; i += 512) {
      int h2p = i >> 6, l = i & 63;
      wvt2[i] = pack2(wvp[l * 64 + 2 * h2p], wvp[l * 64 + 2 * h2p + 1]);
    }
    if (tid < 64) { pD[tid] = ((const float*)(ws + WS_D))[tid];
                    pE[tid] = ((const float*)(ws + WS_E))[tid]; }
    if (tid == 0) pF[0] = *(const float*)(ws + WS_F);
    __syncthreads();

    float* mc = (float*)(lds + P0_MC + wv * MC_BYTES);   // [64][65]
    const float bvl   = bvp[lane];
    const float fscal = pF[0];
    const float* memb = memory + ((size_t)b * MM + (size_t)half * 128) * HD;

    for (int g = 0; g < 2; ++g) {
      WAVE_FENCE();
#pragma unroll 4
      for (int r = 0; r < 64; ++r)
        mc[r * 65 + lane] = memb[(size_t)(g * 64 + r) * HD + lane];
      WAVE_FENCE();

      // K' row m = half*128 + g*64 + lane
      float acc[64];
#pragma unroll
      for (int h = 0; h < 64; ++h) acc[h] = pD[h];
      float cacc = fscal;
      for (int h2 = 0; h2 < 64; ++h2) {
        float mv = mc[lane * 65 + h2];
        cacc = fmaf(mv, pE[h2], cacc);
        const unsigned* wrow = w2p + h2 * 32;
#pragma unroll
        for (int hp = 0; hp < 32; ++hp) {
          unsigned u = wrow[hp];
          acc[2 * hp]     = fmaf(mv, lo16(u), acc[2 * hp]);
          acc[2 * hp + 1] = fmaf(mv, hi16(u), acc[2 * hp + 1]);
        }
      }
      cm[g] = cacc;
#pragma unroll
      for (int u = 0; u < 32; ++u) kp[g][u] = pack2(acc[2 * u], acc[2 * u + 1]);

      // V rows 2rp,2rp+1 of this g at output column o = lane
      for (int rp = 0; rp < 32; ++rp) {
        float a0 = bvl, a1 = bvl;
#pragma unroll
        for (int hq = 0; hq < 32; ++hq) {
          unsigned w = wvt2[hq * 64 + lane];
          float wl = lo16(w), wh = hi16(w);
          const float2 m0 = *(const float2*)&mc[(2 * rp) * 65 + 2 * hq];
          const float2 m1 = *(const float2*)&mc[(2 * rp + 1) * 65 + 2 * hq];
          a0 = fmaf(m0.x, wl, a0); a0 = fmaf(m0.y, wh, a0);
          a1 = fmaf(m1.x, wl, a1); a1 = fmaf(m1.y, wh, a1);
        }
        vt[32 * g + rp] = pack2(a0, a1);
      }
    }
    __syncthreads();
  }

  // ---------------- stage main-phase weights; init dynamic region ----------------
  {
    const float4* s1 = (const float4*)(ws + WS_WPA);   float4* d1 = (float4*)(lds + LD_WPA);
    for (int i = tid; i < 1536; i += 512) d1[i] = s1[i];
    const float4* s2 = (const float4*)(ws + WS_WPB);   float4* d2 = (float4*)(lds + LD_WPB);
    for (int i = tid; i < 1536; i += 512) d2[i] = s2[i];
    const float4* s3 = (const float4*)(ws + WS_G);     float4* d3 = (float4*)(lds + LD_G);
    for (int i = tid; i < 1536; i += 512) d3[i] = s3[i];
    const float4* s4 = (const float4*)(ws + WS_HWT2);  float4* d4 = (float4*)(lds + LD_HWT2);
    for (int i = tid; i < 1024; i += 512) d4[i] = s4[i];
    float* dz = (float*)(lds + LD_DYN);
    for (int i = tid; i < 4096; i += 512) dz[i] = 0.f;
    __syncthreads();
    if (tid < 4) *(float*)(lds + LD_DYN + tid * DYN_STRIDE + DY_SEH) = 1.f;  // Se init
    __syncthreads();
  }

  const unsigned* sWPA = (const unsigned*)(lds + LD_WPA);
  const unsigned* sWPB = (const unsigned*)(lds + LD_WPB);
  const unsigned* sG   = (const unsigned*)(lds + LD_G);
  const float2*   sHW2 = (const float2*)(lds + LD_HWT2);
  unsigned char* dynp = lds + LD_DYN + b_local * DYN_STRIDE;
  float* sGI   = (float*)(dynp + DY_GI);
  float* sGH   = (float*)(dynp + DY_GH);
  float* sHNB  = (float*)(dynp + DY_HNB);
  float* sNUM  = (float*)(dynp + DY_NUM);
  float* sWEXP = (float*)(dynp + DY_WEXP);
  float* sSMAX = (float*)(dynp + DY_SMAX);
  float* sSEH  = (float*)(dynp + DY_SEH);
  unsigned long long* slots = (unsigned long long*)(ws + WS_SLOTS);
  const int* seqb = seq + (size_t)b * LL;

  float h_reg = 0.f;
  int rcount = 0;
  float bh_r = 0.f, bh_z = 0.f, bh_n = 0.f, hb_l = 0.f;
  if (!isA) { bh_r = b_hh[lane]; bh_z = b_hh[64 + lane]; bh_n = b_hh[128 + lane]; }
  else      { hb_l = head_b[lane]; }

  for (int t = 0; t < LL; ++t) {
    float own_r, own_z, own_n;
    if (isA) {
      // gi = G[token] + cond * rcpSe * (num @ Wr^T)
      float Se = sSEH[0] + sSEH[1];
      float rcpSe = 1.0f / Se;
      int token = seqb[t];
      float sr = 0.f, sz = 0.f, sn = 0.f;
#pragma unroll
      for (int q = 0; q < 32; ++q) {
        float2 n0 = *(const float2*)&sNUM[2 * q];
        float2 n1 = *(const float2*)&sNUM[64 + 2 * q];
        float a0 = n0.x + n1.x, a1 = n0.y + n1.y;
        unsigned ur = sWPA[q * 192 + lane];
        unsigned uz = sWPA[q * 192 + 64 + lane];
        unsigned un = sWPA[q * 192 + 128 + lane];
        sr = fmaf(a0, lo16(ur), sr); sr = fmaf(a1, hi16(ur), sr);
        sz = fmaf(a0, lo16(uz), sz); sz = fmaf(a1, hi16(uz), sz);
        sn = fmaf(a0, lo16(un), sn); sn = fmaf(a1, hi16(un), sn);
      }
      bool condp = (t > 0) ? poll_cond(slots, t - 1, lane) : false;
      rcount += condp ? 1 : 0;
      float gsc = condp ? rcpSe : 0.f;
      unsigned gp0 = sG[token * 96 +      (lane >> 1)];
      unsigned gp1 = sG[token * 96 + 32 + (lane >> 1)];
      unsigned gp2 = sG[token * 96 + 64 + (lane >> 1)];
      bool oddl = (lane & 1);
      float g_r = oddl ? hi16(gp0) : lo16(gp0);
      float g_z = oddl ? hi16(gp1) : lo16(gp1);
      float g_n = oddl ? hi16(gp2) : lo16(gp2);
      own_r = fmaf(gsc, sr, g_r);
      own_z = fmaf(gsc, sz, g_z);
      own_n = fmaf(gsc, sn, g_n);
      sGI[lane] = own_r; sGI[64 + lane] = own_z; sGI[128 + lane] = own_n;
    } else {
      // gh = h_prev @ Whh^T + b_hh
      float hr = bh_r, hz = bh_z, hn = bh_n;
#pragma unroll
      for (int q = 0; q < 32; ++q) {
        float2 h01 = *(const float2*)&sHNB[2 * q];
        unsigned ur = sWPB[q * 192 + lane];
        unsigned uz = sWPB[q * 192 + 64 + lane];
        unsigned un = sWPB[q * 192 + 128 + lane];
        hr = fmaf(h01.x, lo16(ur), hr); hr = fmaf(h01.y, hi16(ur), hr);
        hz = fmaf(h01.x, lo16(uz), hz); hz = fmaf(h01.y, hi16(uz), hz);
        hn = fmaf(h01.x, lo16(un), hn); hn = fmaf(h01.y, hi16(un), hn);
      }
      own_r = hr; own_z = hz; own_n = hn;
      sGH[lane] = hr; sGH[64 + lane] = hz; sGH[128 + lane] = hn;
    }
    __syncthreads();   // X: gi/gh exchanged

    float o1, o2, o3;
    if (isA) { o1 = sGH[lane]; o2 = sGH[64 + lane]; o3 = sGH[128 + lane]; }
    else     { o1 = sGI[lane]; o2 = sGI[64 + lane]; o3 = sGI[128 + lane]; }
    float xr = own_r + o1;
    float xz = own_z + o2;
    float gin_v = isA ? own_n : o3;
    float ghn_v = isA ? o3 : own_n;
    float rg = 1.f / (1.f + __expf(-xr));
    float zg = 1.f / (1.f + __expf(-xz));
    float narg = fmaf(rg, ghn_v, gin_v);
    float eee = __expf(-2.f * narg);
    float ng = (1.f - eee) / (1.f + eee);
    float h_new = (1.f - zg) * ng + zg * h_reg;
    if (isA) sHNB[lane] = h_new;
    __syncthreads();   // Y: h_new broadcastable

    if (isA) {
      // entropy gate -> post packed (count|value), relaxed
      float lo = hb_l;
#pragma unroll
      for (int hp = 0; hp < 32; ++hp) {
        float2 h01 = *(const float2*)&sHNB[2 * hp];
        float2 w = sHW2[hp * 64 + lane];
        lo = fmaf(h01.x, w.x, lo); lo = fmaf(h01.y, w.y, lo);
      }
      float mx = lo;
#pragma unroll
      for (int off = 32; off; off >>= 1) mx = fmaxf(mx, __shfl_xor(mx, off, 64));
      float pu = __expf(lo - mx);
      float Ss = pu;
#pragma unroll
      for (int off = 32; off; off >>= 1) Ss += __shfl_xor(Ss, off, 64);
      float pr = pu / Ss;
      float ent = pr * __logf(pr + 1e-8f);
#pragma unroll
      for (int off = 32; off; off >>= 1) ent += __shfl_xor(ent, off, 64);
      if (lane == 0) {
        float be = fmaxf(-ent, 0.f);
        unsigned long long pk = (1ull << 48) | (unsigned long long)(be * 1048576.0f + 0.5f);
        __hip_atomic_fetch_add(&slots[(size_t)grp * LL + t], pk,
                               __ATOMIC_RELAXED, __HIP_MEMORY_SCOPE_AGENT);
      }
    }

    // attention scores for own half (m = half*128 + g*64 + lane)
    float s0 = cm[0], s1 = cm[1];
#pragma unroll
    for (int hp = 0; hp < 32; ++hp) {
      float2 h01 = *(const float2*)&sHNB[2 * hp];
      unsigned u0 = kp[0][hp], u1 = kp[1][hp];
      s0 = fmaf(h01.x, lo16(u0), s0); s0 = fmaf(h01.y, hi16(u0), s0);
      s1 = fmaf(h01.x, lo16(u1), s1); s1 = fmaf(h01.y, hi16(u1), s1);
    }
    s0 *= SCALE_; s1 *= SCALE_;
    float smax = fmaxf(s0, s1);
#pragma unroll
    for (int off = 32; off; off >>= 1) smax = fmaxf(smax, __shfl_xor(smax, off, 64));
    if (lane == 0) sSMAX[half] = smax;
    __syncthreads();   // Z1: half-maxes exchanged

    float gmax = fmaxf(sSMAX[0], sSMAX[1]);
    float e0 = __expf(s0 - gmax), e1 = __expf(s1 - gmax);
    float seh = e0 + e1;
#pragma unroll
    for (int off = 32; off; off >>= 1) seh += __shfl_xor(seh, off, 64);
    sWEXP[half * 128 + lane] = e0;
    sWEXP[half * 128 + 64 + lane] = e1;
    if (lane == 0) sSEH[half] = seh;
    WAVE_FENCE();

    // PV numerator for own half
    float al = 0.f;
    const float4* w4 = (const float4*)(sWEXP + half * 128);
#pragma unroll
    for (int mp = 0; mp < 32; ++mp) {
      float4 wq4 = w4[mp];
      unsigned u0 = vt[2 * mp], u1 = vt[2 * mp + 1];
      al = fmaf(wq4.x, lo16(u0), al);
      al = fmaf(wq4.y, hi16(u0), al);
      al = fmaf(wq4.z, lo16(u1), al);
      al = fmaf(wq4.w, hi16(u1), al);
    }
    sNUM[half * 64 + lane] = al;
    h_reg = h_new;
    __syncthreads();   // W: num/Se published for next step
  }

  if (isA) rcount += poll_cond(slots, LL - 1, lane) ? 1 : 0;

  // final logits with f32 head weights
  if (isA) {
    float lof = hb_l;
#pragma unroll 8
    for (int h = 0; h < 64; ++h) lof = fmaf(sHNB[h], head_w[lane * 64 + h], lof);
    out[(size_t)b * 64 + lane] = lof;
  }
  if (blockIdx.x == 0 && tid == 0) out[BB * 64] = (float)rcount / (float)LL;
}

// =====================================================================
extern "C" void kernel_launch(void* const* d_in, const int* in_sizes, int n_in,
                              void* d_out, int out_size, void* d_ws, size_t ws_size,
                              hipStream_t stream)
{
  (void)in_sizes; (void)n_in; (void)out_size; (void)ws_size;
  const int*   seq    = (const int*)  d_in[0];
  const float* memory = (const float*)d_in[1];
  const float* embed  = (const float*)d_in[2];
  const float* w_ih   = (const float*)d_in[3];
  const float* w_hh   = (const float*)d_in[4];
  const float* b_ih   = (const float*)d_in[5];
  const float* b_hh   = (const float*)d_in[6];
  const float* wq     = (const float*)d_in[7];
  const float* bq     = (const float*)d_in[8];
  const float* wk     = (const float*)d_in[9];
  const float* bk     = (const float*)d_in[10];
  const float* wv     = (const float*)d_in[11];
  const float* bv     = (const float*)d_in[12];
  const float* head_w = (const float*)d_in[13];
  const float* head_b = (const float*)d_in[14];
  unsigned char* ws   = (unsigned char*)d_ws;
  float* out          = (float*)d_out;

  hipMemsetAsync(d_ws, 0, NGROUP * LL * sizeof(unsigned long long), stream);

  hipLaunchKernelGGL(reactive_pre, dim3(1), dim3(1024), 0, stream,
                     embed, w_ih, w_hh, b_ih, wq, bq, wk, bk, head_w, ws);

  hipFuncSetAttribute((const void*)reactive_main,
                      hipFuncAttributeMaxDynamicSharedMemorySize, LDS_BYTES);
  hipLaunchKernelGGL(reactive_main, dim3(256), dim3(512), LDS_BYTES, stream,
                     seq, memory, wv, bv, b_hh, head_w, head_b, ws, out);
}

// Round 4
// 32731.976 us; speedup vs baseline: 1.0703x; 1.0703x over previous
//
#include <hip/hip_runtime.h>
#include <stdint.h>

// Problem constants
#define HD       64
#define MM       256
#define BB       1024
#define LL       2048
#define SCALE_   0.125f
#define GATE_SUM (2560ull << 20)   // sum of 1024 fixed-point(2^20) entropies > 2560

// ---------------- workspace (d_ws) layout, bytes ----------------
#define WS_SLOTS 0           // 64 groups * 2 parities * 64B = 8192 (zeroed each launch)
#define WS_WPA   8192        // [32 kp][3 g][64 j] u32 bf16-pairs of w_ih r-cols (24576)
#define WS_WPB   32768       // [32 kp][3 g][64 j] u32 bf16-pairs of w_hh       (24576)
#define WS_G     57344       // [64 tok][96] u32 bf16 pairs: embed@Wx^T + b_ih  (24576)
#define WS_HWT2  81920       // [32 hp][64 o] float2 head_w pairs over h        (16384)
#define WS_W2    98304       // [64][64] f32 wk^T@wq                            (16384)
#define WS_D     114688      // [64] f32 bk@wq
#define WS_E     114944      // [64] f32 bq@wk
#define WS_F     115200      // f32 bq.bk

// ---------------- main-phase LDS layout ----------------
#define LD_WPA   0           // 24576
#define LD_WPB   24576       // 24576
#define LD_G     49152       // 24576
#define LD_HWT2  73728       // 16384
#define LD_DYN   90112       // 4 b * 4096
#define DYN_STRIDE 4096
#define DY_GI    0           // 3*64 f32
#define DY_GH    768         // 3*64 f32
#define DY_HA    1536        // 64 f32 (A's private h)
#define DY_HB    1792        // 64 f32 (B's private h)
#define DY_NUM   2048        // 2*64 f32 (PV numerator halves)
#define DY_WEA   2560        // 128 f32 (A's exp weights)
#define DY_WEB   3072        // 128 f32 (B's exp weights)
#define DY_SEH   3584        // 2 f32
#define LD_MISC  106496      // sBEC u32 @0, sCONDW u32 @4

// ---------------- phase-0 overlay ----------------
#define P0_W2P   0           // 8192  bf16 pairs of W2 over h
#define P0_WVT2  8192        // 8192  bf16 pairs of wv^T over h2
#define P0_D     16384
#define P0_E     16640
#define P0_F     16896
#define P0_MC    17408       // + wv*16640 : [64][65] f32 memory chunk
#define MC_BYTES 16640

#define LDS_BYTES 150528

__device__ __forceinline__ unsigned bf16r(float x) {
  unsigned u = __float_as_uint(x);
  return (u + 0x7fffu + ((u >> 16) & 1u)) >> 16;
}
__device__ __forceinline__ unsigned pack2(float a, float b) {
  return bf16r(a) | (bf16r(b) << 16);
}
__device__ __forceinline__ float lo16(unsigned u) { return __uint_as_float(u << 16); }
__device__ __forceinline__ float hi16(unsigned u) { return __uint_as_float(u & 0xffff0000u); }

#define WAVE_FENCE() asm volatile("s_waitcnt lgkmcnt(0)" ::: "memory")

// Grid gate for step s, done by ONE wave per block. Lane l owns group l.
// Slots are cumulative (count<<48 | sum); detect when this step's delta count==4.
// Ring-2 by parity is race-free: a post for s+2 can only occur after every
// block finished polling s.
__device__ __forceinline__ bool poll2(const unsigned long long* slots, int s, int lane,
                                      unsigned long long& prevA, unsigned long long& prevB) {
  const int par = s & 1;
  const unsigned long long* p = slots + ((size_t)lane * 2 + par) * 8;
  unsigned long long prev = par ? prevB : prevA;
  unsigned long long cur;
  for (;;) {
    cur = __hip_atomic_load(p, __ATOMIC_RELAXED, __HIP_MEMORY_SCOPE_AGENT);
    if (__all((int)((cur - prev) >> 48) == 4)) break;
    __builtin_amdgcn_s_sleep(2);
  }
  if (par) prevB = cur; else prevA = cur;
  unsigned long long sd = (cur - prev) & 0xFFFFFFFFFFFFull;
#pragma unroll
  for (int off = 32; off; off >>= 1) sd += __shfl_xor(sd, off, 64);
  return sd > GATE_SUM;
}

// =====================================================================
// P1: one-time weight preprocessing into workspace
// =====================================================================
extern "C" __global__ void reactive_pre(
    const float* __restrict__ embed, const float* __restrict__ w_ih,
    const float* __restrict__ w_hh,  const float* __restrict__ b_ih,
    const float* __restrict__ wq,    const float* __restrict__ bq,
    const float* __restrict__ wk,    const float* __restrict__ bk,
    const float* __restrict__ head_w, unsigned char* __restrict__ ws)
{
  const int tid = threadIdx.x;  // 1024 threads, 1 block

  unsigned* wpa = (unsigned*)(ws + WS_WPA);
  unsigned* wpb = (unsigned*)(ws + WS_WPB);
  for (int i = tid; i < 6144; i += 1024) {
    int q = i / 192, row = i % 192;      // [kp][g*64+j]
    wpa[i] = pack2(w_ih[row * 128 + 64 + 2 * q], w_ih[row * 128 + 64 + 2 * q + 1]);
    wpb[i] = pack2(w_hh[row * 64 + 2 * q],       w_hh[row * 64 + 2 * q + 1]);
  }
  unsigned* gp = (unsigned*)(ws + WS_G);
  for (int i = tid; i < 64 * 96; i += 1024) {
    int v = i / 96, u = i % 96;
    int j0 = 2 * u, j1 = j0 + 1;
    float g0 = b_ih[j0], g1 = b_ih[j1];
    for (int h = 0; h < 64; ++h) {
      float ev = embed[v * 64 + h];
      g0 = fmaf(ev, w_ih[j0 * 128 + h], g0);
      g1 = fmaf(ev, w_ih[j1 * 128 + h], g1);
    }
    gp[i] = pack2(g0, g1);
  }
  float2* hwt2 = (float2*)(ws + WS_HWT2);
  for (int i = tid; i < 2048; i += 1024) {
    int hp = i >> 6, o = i & 63;
    hwt2[i] = make_float2(head_w[o * 64 + 2 * hp], head_w[o * 64 + 2 * hp + 1]);
  }
  float* w2 = (float*)(ws + WS_W2);
  for (int i = tid; i < 4096; i += 1024) {
    int h2 = i >> 6, h = i & 63;
    float a = 0.f;
    for (int o = 0; o < 64; ++o) a = fmaf(wk[o * 64 + h2], wq[o * 64 + h], a);
    w2[i] = a;
  }
  if (tid < 64) {
    float a = 0.f, b2 = 0.f;
    for (int o = 0; o < 64; ++o) a  = fmaf(bk[o], wq[o * 64 + tid], a);
    for (int o = 0; o < 64; ++o) b2 = fmaf(bq[o], wk[o * 64 + tid], b2);
    ((float*)(ws + WS_D))[tid] = a;
    ((float*)(ws + WS_E))[tid] = b2;
  }
  if (tid == 0) {
    float a = 0.f;
    for (int o = 0; o < 64; ++o) a = fmaf(bq[o], bk[o], a);
    *(float*)(ws + WS_F) = a;
  }
}

// =====================================================================
// Main persistent kernel: 256 blocks x 512 threads (8 waves = 4 b's x {A,B}).
// Wave A: gi(att) + gate + entropy + post/poll. Wave B: gh.
// 2 block barriers/step (X: gi/gh exchange, W: PV publish).
// Grid sync: LDS combine -> 1 far-atomic/block into 64-group ring-2 slots,
// 1 poller wave/block, LDS cond broadcast.
// =====================================================================
extern "C" __global__ void __launch_bounds__(512, 2)
reactive_main(const int* __restrict__ seq, const float* __restrict__ memory,
              const float* __restrict__ wvp, const float* __restrict__ bvp,
              const float* __restrict__ b_hh, const float* __restrict__ head_w,
              const float* __restrict__ head_b, unsigned char* __restrict__ ws,
              float* __restrict__ out)
{
  extern __shared__ __align__(16) unsigned char lds[];
  const int tid     = threadIdx.x;
  const int wv      = tid >> 6;
  const int lane    = tid & 63;
  const int half    = wv >> 2;       // 0 = A, 1 = B
  const int b_local = wv & 3;
  const int b       = (int)blockIdx.x * 4 + b_local;
  const int grp     = (int)blockIdx.x & 63;
  const bool isA    = (half == 0);

  unsigned kp[2][32];   // K' bf16 pairs for m = half*128 + g*64 + lane
  unsigned vt[64];      // V bf16 pairs over this half's 128 m-rows
  float    cm[2];

  // ---------------- phase 0: per-(b,half) K', V^T, c into registers ----------------
  {
    unsigned* w2p  = (unsigned*)(lds + P0_W2P);
    unsigned* wvt2 = (unsigned*)(lds + P0_WVT2);
    float* pD = (float*)(lds + P0_D);
    float* pE = (float*)(lds + P0_E);
    float* pF = (float*)(lds + P0_F);
    const float* wsW2 = (const float*)(ws + WS_W2);
    for (int i = tid; i < 2048; i += 512) {
      int h2 = i >> 5, hp = i & 31;
      w2p[i] = pack2(wsW2[h2 * 64 + 2 * hp], wsW2[h2 * 64 + 2 * hp + 1]);
    }
    for (int i = tid; i < 2048; i += 512) {
      int h2p = i >> 6, l = i & 63;
      wvt2[i] = pack2(wvp[l * 64 + 2 * h2p], wvp[l * 64 + 2 * h2p + 1]);
    }
    if (tid < 64) { pD[tid] = ((const float*)(ws + WS_D))[tid];
                    pE[tid] = ((const float*)(ws + WS_E))[tid]; }
    if (tid == 0) pF[0] = *(const float*)(ws + WS_F);
    __syncthreads();

    float* mc = (float*)(lds + P0_MC + wv * MC_BYTES);   // [64][65]
    const float bvl   = bvp[lane];
    const float fscal = pF[0];
    const float* memb = memory + ((size_t)b * MM + (size_t)half * 128) * HD;

    for (int g = 0; g < 2; ++g) {
      WAVE_FENCE();
#pragma unroll 4
      for (int r = 0; r < 64; ++r)
        mc[r * 65 + lane] = memb[(size_t)(g * 64 + r) * HD + lane];
      WAVE_FENCE();

      float acc[64];
#pragma unroll
      for (int h = 0; h < 64; ++h) acc[h] = pD[h];
      float cacc = fscal;
      for (int h2 = 0; h2 < 64; ++h2) {
        float mv = mc[lane * 65 + h2];
        cacc = fmaf(mv, pE[h2], cacc);
        const unsigned* wrow = w2p + h2 * 32;
#pragma unroll
        for (int hp = 0; hp < 32; ++hp) {
          unsigned u = wrow[hp];
          acc[2 * hp]     = fmaf(mv, lo16(u), acc[2 * hp]);
          acc[2 * hp + 1] = fmaf(mv, hi16(u), acc[2 * hp + 1]);
        }
      }
      cm[g] = cacc;
#pragma unroll
      for (int u = 0; u < 32; ++u) kp[g][u] = pack2(acc[2 * u], acc[2 * u + 1]);

      for (int rp = 0; rp < 32; ++rp) {
        float a0 = bvl, a1 = bvl;
#pragma unroll
        for (int hq = 0; hq < 32; ++hq) {
          unsigned w = wvt2[hq * 64 + lane];
          float wl = lo16(w), wh = hi16(w);
          const float2 m0 = *(const float2*)&mc[(2 * rp) * 65 + 2 * hq];
          const float2 m1 = *(const float2*)&mc[(2 * rp + 1) * 65 + 2 * hq];
          a0 = fmaf(m0.x, wl, a0); a0 = fmaf(m0.y, wh, a0);
          a1 = fmaf(m1.x, wl, a1); a1 = fmaf(m1.y, wh, a1);
        }
        vt[32 * g + rp] = pack2(a0, a1);
      }
    }
    __syncthreads();
  }

  // ---------------- stage main-phase weights; init dynamic region ----------------
  {
    const float4* s1 = (const float4*)(ws + WS_WPA);   float4* d1 = (float4*)(lds + LD_WPA);
    for (int i = tid; i < 1536; i += 512) d1[i] = s1[i];
    const float4* s2 = (const float4*)(ws + WS_WPB);   float4* d2 = (float4*)(lds + LD_WPB);
    for (int i = tid; i < 1536; i += 512) d2[i] = s2[i];
    const float4* s3 = (const float4*)(ws + WS_G);     float4* d3 = (float4*)(lds + LD_G);
    for (int i = tid; i < 1536; i += 512) d3[i] = s3[i];
    const float4* s4 = (const float4*)(ws + WS_HWT2);  float4* d4 = (float4*)(lds + LD_HWT2);
    for (int i = tid; i < 1024; i += 512) d4[i] = s4[i];
    float* dz = (float*)(lds + LD_DYN);
    for (int i = tid; i < 4096; i += 512) dz[i] = 0.f;
    if (tid < 2) ((unsigned*)(lds + LD_MISC))[tid] = 0u;
    __syncthreads();
    if (tid < 4) *(float*)(lds + LD_DYN + tid * DYN_STRIDE + DY_SEH) = 1.f;  // Se init
    __syncthreads();
  }

  const unsigned* sWPA = (const unsigned*)(lds + LD_WPA);
  const unsigned* sWPB = (const unsigned*)(lds + LD_WPB);
  const unsigned* sG   = (const unsigned*)(lds + LD_G);
  const float2*   sHW2 = (const float2*)(lds + LD_HWT2);
  unsigned char* dynp = lds + LD_DYN + b_local * DYN_STRIDE;
  float* sGI  = (float*)(dynp + DY_GI);
  float* sGH  = (float*)(dynp + DY_GH);
  float* sHA  = (float*)(dynp + DY_HA);
  float* sHB  = (float*)(dynp + DY_HB);
  float* sNUM = (float*)(dynp + DY_NUM);
  float* sWE  = (float*)(dynp + (isA ? DY_WEA : DY_WEB));
  float* sSEH = (float*)(dynp + DY_SEH);
  float* sHme = isA ? sHA : sHB;
  volatile unsigned* sBEC   = (volatile unsigned*)(lds + LD_MISC);
  volatile unsigned* sCONDW = (volatile unsigned*)(lds + LD_MISC + 4);
  unsigned long long* slots = (unsigned long long*)(ws + WS_SLOTS);
  const int* seqb = seq + (size_t)b * LL;

  float h_reg = 0.f;
  int rcount = 0;
  unsigned long long prevA = 0ull, prevB = 0ull;
  float bh_r = 0.f, bh_z = 0.f, bh_n = 0.f, hb_l = 0.f;
  if (!isA) { bh_r = b_hh[lane]; bh_z = b_hh[64 + lane]; bh_n = b_hh[128 + lane]; }
  else      { hb_l = head_b[lane]; }

  for (int t = 0; t < LL; ++t) {
    float own_r, own_z, own_n;
    if (isA) {
      // ---- gi = G[token] + cond_{t-1}/Se * (num @ Wr^T) (speculative partial) ----
      float Se = sSEH[0] + sSEH[1];
      float rcpSe = 1.0f / Se;
      int token = seqb[t];
      float sr = 0.f, sz = 0.f, sn = 0.f;
#pragma unroll
      for (int q = 0; q < 32; ++q) {
        float2 n0 = *(const float2*)&sNUM[2 * q];
        float2 n1 = *(const float2*)&sNUM[64 + 2 * q];
        float a0 = n0.x + n1.x, a1 = n0.y + n1.y;
        unsigned ur = sWPA[q * 192 + lane];
        unsigned uz = sWPA[q * 192 + 64 + lane];
        unsigned un = sWPA[q * 192 + 128 + lane];
        sr = fmaf(a0, lo16(ur), sr); sr = fmaf(a1, hi16(ur), sr);
        sz = fmaf(a0, lo16(uz), sz); sz = fmaf(a1, hi16(uz), sz);
        sn = fmaf(a0, lo16(un), sn); sn = fmaf(a1, hi16(un), sn);
      }
      // ---- resolve cond_{t-1}: wv0 polls globally, others spin on LDS ----
      bool condp;
      if (wv == 0) {
        condp = (t > 0) ? poll2(slots, t - 1, lane, prevA, prevB) : false;
        if (lane == 0) *sCONDW = ((unsigned)(t + 1) << 1) | (condp ? 1u : 0u);
      } else {
        unsigned cv;
        do { cv = *sCONDW; if ((cv >> 1) != (unsigned)(t + 1)) __builtin_amdgcn_s_sleep(1); }
        while ((cv >> 1) != (unsigned)(t + 1));
        condp = (cv & 1u) != 0u;
      }
      rcount += condp ? 1 : 0;
      float gsc = condp ? rcpSe : 0.f;
      unsigned gp0 = sG[token * 96 +      (lane >> 1)];
      unsigned gp1 = sG[token * 96 + 32 + (lane >> 1)];
      unsigned gp2 = sG[token * 96 + 64 + (lane >> 1)];
      bool oddl = (lane & 1);
      float g_r = oddl ? hi16(gp0) : lo16(gp0);
      float g_z = oddl ? hi16(gp1) : lo16(gp1);
      float g_n = oddl ? hi16(gp2) : lo16(gp2);
      own_r = fmaf(gsc, sr, g_r);
      own_z = fmaf(gsc, sz, g_z);
      own_n = fmaf(gsc, sn, g_n);
      sGI[lane] = own_r; sGI[64 + lane] = own_z; sGI[128 + lane] = own_n;
    } else {
      // ---- gh = h_prev @ Whh^T + b_hh (reads own private h copy) ----
      float hr = bh_r, hz = bh_z, hn = bh_n;
#pragma unroll
      for (int q = 0; q < 32; ++q) {
        float2 h01 = *(const float2*)&sHB[2 * q];
        unsigned ur = sWPB[q * 192 + lane];
        unsigned uz = sWPB[q * 192 + 64 + lane];
        unsigned un = sWPB[q * 192 + 128 + lane];
        hr = fmaf(h01.x, lo16(ur), hr); hr = fmaf(h01.y, hi16(ur), hr);
        hz = fmaf(h01.x, lo16(uz), hz); hz = fmaf(h01.y, hi16(uz), hz);
        hn = fmaf(h01.x, lo16(un), hn); hn = fmaf(h01.y, hi16(un), hn);
      }
      own_r = hr; own_z = hz; own_n = hn;
      sGH[lane] = hr; sGH[64 + lane] = hz; sGH[128 + lane] = hn;
    }
    __syncthreads();   // X: gi/gh exchanged

    // ---- gates + h_new (computed redundantly, bit-identical on A and B) ----
    float o1, o2, o3;
    if (isA) { o1 = sGH[lane]; o2 = sGH[64 + lane]; o3 = sGH[128 + lane]; }
    else     { o1 = sGI[lane]; o2 = sGI[64 + lane]; o3 = sGI[128 + lane]; }
    float xr = own_r + o1;
    float xz = own_z + o2;
    float gin_v = isA ? own_n : o3;
    float ghn_v = isA ? o3 : own_n;
    float rg = 1.f / (1.f + __expf(-xr));
    float zg = 1.f / (1.f + __expf(-xz));
    float narg = fmaf(rg, ghn_v, gin_v);
    float eee = __expf(-2.f * narg);
    float ng = (1.f - eee) / (1.f + eee);
    float h_new = (1.f - zg) * ng + zg * h_reg;
    sHme[lane] = h_new;   // own private copy (wave-local)
    WAVE_FENCE();

    if (isA) {
      // ---- entropy gate -> LDS combine -> 1 far-atomic per block ----
      float lo = hb_l;
#pragma unroll
      for (int hp = 0; hp < 32; ++hp) {
        float2 h01 = *(const float2*)&sHA[2 * hp];
        float2 w = sHW2[hp * 64 + lane];
        lo = fmaf(h01.x, w.x, lo); lo = fmaf(h01.y, w.y, lo);
      }
      float pu = __expf(lo);
      float Ss = pu;
#pragma unroll
      for (int off = 32; off; off >>= 1) Ss += __shfl_xor(Ss, off, 64);
      float pr = pu / Ss;
      float ent = pr * __logf(pr + 1e-8f);
#pragma unroll
      for (int off = 32; off; off >>= 1) ent += __shfl_xor(ent, off, 64);
      if (lane == 0) {
        float be = fmaxf(-ent, 0.f);
        unsigned fp = (unsigned)(be * 1048576.0f + 0.5f);
        unsigned add = (1u << 28) | fp;
        unsigned old = atomicAdd((unsigned*)sBEC, add);
        if ((old >> 28) == 3u) {   // 4th wave: publish block sum, reset
          unsigned tot = (old + add) & 0x0FFFFFFFu;
          __hip_atomic_fetch_add(&slots[(size_t)grp * 16 + (size_t)(t & 1) * 8],
                                 (1ull << 48) | (unsigned long long)tot,
                                 __ATOMIC_RELAXED, __HIP_MEMORY_SCOPE_AGENT);
          *sBEC = 0u;
        }
      }
    }

    // ---- attention scores for own half (no max subtraction; bounded) ----
    float s0 = cm[0], s1 = cm[1];
#pragma unroll
    for (int hp = 0; hp < 32; ++hp) {
      float2 h01 = *(const float2*)&sHme[2 * hp];
      unsigned u0 = kp[0][hp], u1 = kp[1][hp];
      s0 = fmaf(h01.x, lo16(u0), s0); s0 = fmaf(h01.y, hi16(u0), s0);
      s1 = fmaf(h01.x, lo16(u1), s1); s1 = fmaf(h01.y, hi16(u1), s1);
    }
    float e0 = __expf(s0 * SCALE_), e1 = __expf(s1 * SCALE_);
    float seh = e0 + e1;
#pragma unroll
    for (int off = 32; off; off >>= 1) seh += __shfl_xor(seh, off, 64);
    sWE[lane] = e0; sWE[64 + lane] = e1;
    if (lane == 0) sSEH[half] = seh;
    WAVE_FENCE();

    // ---- PV numerator for own half (reads own wave-private sWE) ----
    float al = 0.f;
    const float4* w4 = (const float4*)sWE;
#pragma unroll
    for (int mp = 0; mp < 32; ++mp) {
      float4 wq4 = w4[mp];
      unsigned u0 = vt[2 * mp], u1 = vt[2 * mp + 1];
      al = fmaf(wq4.x, lo16(u0), al);
      al = fmaf(wq4.y, hi16(u0), al);
      al = fmaf(wq4.z, lo16(u1), al);
      al = fmaf(wq4.w, hi16(u1), al);
    }
    sNUM[half * 64 + lane] = al;
    h_reg = h_new;
    __syncthreads();   // W: num/Se published for next step's A phase
  }

  // resolve final step's cond (only needed for read_rate, block 0)
  if (blockIdx.x == 0 && wv == 0) {
    rcount += poll2(slots, LL - 1, lane, prevA, prevB) ? 1 : 0;
    if (lane == 0) out[BB * 64] = (float)rcount / (float)LL;
  }

  // final logits with f32 head weights
  if (isA) {
    float lof = hb_l;
#pragma unroll 8
    for (int h = 0; h < 64; ++h) lof = fmaf(sHA[h], head_w[lane * 64 + h], lof);
    out[(size_t)b * 64 + lane] = lof;
  }
}

// =====================================================================
extern "C" void kernel_launch(void* const* d_in, const int* in_sizes, int n_in,
                              void* d_out, int out_size, void* d_ws, size_t ws_size,
                              hipStream_t stream)
{
  (void)in_sizes; (void)n_in; (void)out_size; (void)ws_size;
  const int*   seq    = (const int*)  d_in[0];
  const float* memory = (const float*)d_in[1];
  const float* embed  = (const float*)d_in[2];
  const float* w_ih   = (const float*)d_in[3];
  const float* w_hh   = (const float*)d_in[4];
  const float* b_ih   = (const float*)d_in[5];
  const float* b_hh   = (const float*)d_in[6];
  const float* wq     = (const float*)d_in[7];
  const float* bq     = (const float*)d_in[8];
  const float* wk     = (const float*)d_in[9];
  const float* bk     = (const float*)d_in[10];
  const float* wv     = (const float*)d_in[11];
  const float* bv     = (const float*)d_in[12];
  const float* head_w = (const float*)d_in[13];
  const float* head_b = (const float*)d_in[14];
  unsigned char* ws   = (unsigned char*)d_ws;
  float* out          = (float*)d_out;

  // zero the cumulative gate slots every call (graph-safe)
  hipMemsetAsync(d_ws, 0, 8192, stream);

  hipLaunchKernelGGL(reactive_pre, dim3(1), dim3(1024), 0, stream,
                     embed, w_ih, w_hh, b_ih, wq, bq, wk, bk, head_w, ws);

  hipFuncSetAttribute((const void*)reactive_main,
                      hipFuncAttributeMaxDynamicSharedMemorySize, LDS_BYTES);
  hipLaunchKernelGGL(reactive_main, dim3(256), dim3(512), LDS_BYTES, stream,
                     seq, memory, wv, bv, b_hh, head_w, head_b, ws, out);
}

// Round 6
// 21068.393 us; speedup vs baseline: 1.6628x; 1.5536x over previous
//
#include <hip/hip_runtime.h>
#include <stdint.h>

// Problem constants
#define HD       64
#define MM       256
#define BB       1024
#define LL       2048
#define SCALE_   0.125f
#define GATE_SUM (2560ull << 20)   // sum of 1024 fixed-point(2^20) entropies > 2560
#define M30      0x3FFFFFFFull
#define M48      0xFFFFFFFFFFFFull
#define SPIN_FAR 16384             // safety escape for far polls (legit waits ~200 iters)
#define SPIN_LDS (1 << 20)

// ---------------- workspace (d_ws) layout, bytes ----------------
// slots: 64 groups * 2 parities, one 64B line each; line: u64[0]=cum(cnt<<48|sumE0),
//        u64[1]=cum(cnt<<48|sumE1).  parity = step & 1 (ring-2, race-free: posts for
//        step t+2 cannot exist until the resolver re-baselined step t).
#define WS_SLOTS 0           // 8192
#define WS_MIRR  8192        // 64 mirror lines * 64B: u64 = (resolved_t)<<32 | condbits
#define WS_WPA   12288       // [32 kp][3 g][64 j] u32 bf16-pairs of w_ih r-cols (24576)
#define WS_WPB   36864       // [32 kp][3 g][64 j] u32 bf16-pairs of w_hh       (24576)
#define WS_G     61440       // [64 tok][96] u32 bf16 pairs: embed@Wx^T + b_ih  (24576)
#define WS_HWT2  86016       // [32 hp][64 o] float2 head_w pairs over h        (16384)
#define WS_W2    102400      // [64][64] f32 wk^T@wq                            (16384)
#define WS_D     118784      // [64] f32 bk@wq
#define WS_E     119040      // [64] f32 bq@wk
#define WS_F     119296      // f32 bq.bk

// ---------------- main-phase LDS layout ----------------
#define LD_WPA   0           // 24576
#define LD_WPB   24576       // 24576
#define LD_G     49152       // 24576
#define LD_HWT2  73728       // 16384
#define LD_DYN   90112       // 4 b * 5120
#define DYN_STRIDE 5120
#define DY_GI    0           // 6*64 f32: gi0 r,z,n then datt r,z,n
#define DY_GH    1536        // 3*64 f32
#define DY_H0A   2304        // 64 f32 (A's h0 copy)
#define DY_H1A   2560        // 64 f32 (A's h1 copy)
#define DY_H0B   2816        // 64 f32 (B's h0 copy)
#define DY_H1B   3072        // 64 f32 (B's h1 copy)
#define DY_NUM   3328        // 2*64 f32 (PV numerator halves)
#define DY_WEA   3840        // 128 f32 (A's exp weights)
#define DY_WEB   4352        // 128 f32 (B's exp weights)
#define DY_SEH   4864        // 2 f32
#define LD_MISC  110592      // sBEC u64[2] @0, sCONDW u32 @16

// ---------------- phase-0 overlay ----------------
#define P0_W2P   0           // 8192  bf16 pairs of W2 over h
#define P0_WVT2  8192        // 8192  bf16 pairs of wv^T over h2
#define P0_D     16384
#define P0_E     16640
#define P0_F     16896
#define P0_MC    17408       // + wv*16640 : [64][65] f32 memory chunk
#define MC_BYTES 16640

#define LDS_BYTES 150528

__device__ __forceinline__ unsigned bf16r(float x) {
  unsigned u = __float_as_uint(x);
  return (u + 0x7fffu + ((u >> 16) & 1u)) >> 16;
}
__device__ __forceinline__ unsigned pack2(float a, float b) {
  return bf16r(a) | (bf16r(b) << 16);
}
__device__ __forceinline__ float lo16(unsigned u) { return __uint_as_float(u << 16); }
__device__ __forceinline__ float hi16(unsigned u) { return __uint_as_float(u & 0xffff0000u); }

#define WAVE_FENCE() asm volatile("s_waitcnt lgkmcnt(0)" ::: "memory")

// =====================================================================
// P1: one-time weight preprocessing into workspace (unchanged)
// =====================================================================
extern "C" __global__ void reactive_pre(
    const float* __restrict__ embed, const float* __restrict__ w_ih,
    const float* __restrict__ w_hh,  const float* __restrict__ b_ih,
    const float* __restrict__ wq,    const float* __restrict__ bq,
    const float* __restrict__ wk,    const float* __restrict__ bk,
    const float* __restrict__ head_w, unsigned char* __restrict__ ws)
{
  const int tid = threadIdx.x;  // 1024 threads, 1 block

  unsigned* wpa = (unsigned*)(ws + WS_WPA);
  unsigned* wpb = (unsigned*)(ws + WS_WPB);
  for (int i = tid; i < 6144; i += 1024) {
    int q = i / 192, row = i % 192;
    wpa[i] = pack2(w_ih[row * 128 + 64 + 2 * q], w_ih[row * 128 + 64 + 2 * q + 1]);
    wpb[i] = pack2(w_hh[row * 64 + 2 * q],       w_hh[row * 64 + 2 * q + 1]);
  }
  unsigned* gp = (unsigned*)(ws + WS_G);
  for (int i = tid; i < 64 * 96; i += 1024) {
    int v = i / 96, u = i % 96;
    int j0 = 2 * u, j1 = j0 + 1;
    float g0 = b_ih[j0], g1 = b_ih[j1];
    for (int h = 0; h < 64; ++h) {
      float ev = embed[v * 64 + h];
      g0 = fmaf(ev, w_ih[j0 * 128 + h], g0);
      g1 = fmaf(ev, w_ih[j1 * 128 + h], g1);
    }
    gp[i] = pack2(g0, g1);
  }
  float2* hwt2 = (float2*)(ws + WS_HWT2);
  for (int i = tid; i < 2048; i += 1024) {
    int hp = i >> 6, o = i & 63;
    hwt2[i] = make_float2(head_w[o * 64 + 2 * hp], head_w[o * 64 + 2 * hp + 1]);
  }
  float* w2 = (float*)(ws + WS_W2);
  for (int i = tid; i < 4096; i += 1024) {
    int h2 = i >> 6, h = i & 63;
    float a = 0.f;
    for (int o = 0; o < 64; ++o) a = fmaf(wk[o * 64 + h2], wq[o * 64 + h], a);
    w2[i] = a;
  }
  if (tid < 64) {
    float a = 0.f, b2 = 0.f;
    for (int o = 0; o < 64; ++o) a  = fmaf(bk[o], wq[o * 64 + tid], a);
    for (int o = 0; o < 64; ++o) b2 = fmaf(bq[o], wk[o * 64 + tid], b2);
    ((float*)(ws + WS_D))[tid] = a;
    ((float*)(ws + WS_E))[tid] = b2;
  }
  if (tid == 0) {
    float a = 0.f;
    for (int o = 0; o < 64; ++o) a = fmaf(bq[o], bk[o], a);
    *(float*)(ws + WS_F) = a;
  }
}

// =====================================================================
// Main persistent kernel: 256 blocks x 512 threads (8 waves = 4 b's x {A,B}).
// 1-step speculative cond: both GRU branches computed, entropy PAIR posted
// before cond(t-1) is needed; block0/wv0 resolves the scalar cond chain and
// publishes a (tag|bitstream) mirror. Slot lines are parity-ringed so the
// resolver's ==4 count check can never mix posts of different steps.
// =====================================================================
extern "C" __global__ void __launch_bounds__(512, 2)
reactive_main(const int* __restrict__ seq, const float* __restrict__ memory,
              const float* __restrict__ wvp, const float* __restrict__ bvp,
              const float* __restrict__ b_hh, const float* __restrict__ head_w,
              const float* __restrict__ head_b, unsigned char* __restrict__ ws,
              float* __restrict__ out)
{
  extern __shared__ __align__(16) unsigned char lds[];
  const int tid     = threadIdx.x;
  const int wv      = tid >> 6;
  const int lane    = tid & 63;
  const int half    = wv >> 2;       // 0 = A, 1 = B
  const int b_local = wv & 3;
  const int b       = (int)blockIdx.x * 4 + b_local;
  const int grp     = (int)blockIdx.x & 63;
  const bool isA    = (half == 0);
  const bool isRes  = (blockIdx.x == 0) && (wv == 0);

  unsigned kp[2][32];   // K' bf16 pairs for m = half*128 + g*64 + lane
  unsigned vt[64];      // V bf16 pairs over this half's 128 m-rows
  float    cm[2];

  // ---------------- phase 0: per-(b,half) K', V^T, c into registers ----------------
  {
    unsigned* w2p  = (unsigned*)(lds + P0_W2P);
    unsigned* wvt2 = (unsigned*)(lds + P0_WVT2);
    float* pD = (float*)(lds + P0_D);
    float* pE = (float*)(lds + P0_E);
    float* pF = (float*)(lds + P0_F);
    const float* wsW2 = (const float*)(ws + WS_W2);
    for (int i = tid; i < 2048; i += 512) {
      int h2 = i >> 5, hp = i & 31;
      w2p[i] = pack2(wsW2[h2 * 64 + 2 * hp], wsW2[h2 * 64 + 2 * hp + 1]);
    }
    for (int i = tid; i < 2048; i += 512) {
      int h2p = i >> 6, l = i & 63;
      wvt2[i] = pack2(wvp[l * 64 + 2 * h2p], wvp[l * 64 + 2 * h2p + 1]);
    }
    if (tid < 64) { pD[tid] = ((const float*)(ws + WS_D))[tid];
                    pE[tid] = ((const float*)(ws + WS_E))[tid]; }
    if (tid == 0) pF[0] = *(const float*)(ws + WS_F);
    __syncthreads();

    float* mc = (float*)(lds + P0_MC + wv * MC_BYTES);   // [64][65]
    const float bvl   = bvp[lane];
    const float fscal = pF[0];
    const float* memb = memory + ((size_t)b * MM + (size_t)half * 128) * HD;

    for (int g = 0; g < 2; ++g) {
      WAVE_FENCE();
#pragma unroll 4
      for (int r = 0; r < 64; ++r)
        mc[r * 65 + lane] = memb[(size_t)(g * 64 + r) * HD + lane];
      WAVE_FENCE();

      float acc[64];
#pragma unroll
      for (int h = 0; h < 64; ++h) acc[h] = pD[h];
      float cacc = fscal;
      for (int h2 = 0; h2 < 64; ++h2) {
        float mv = mc[lane * 65 + h2];
        cacc = fmaf(mv, pE[h2], cacc);
        const unsigned* wrow = w2p + h2 * 32;
#pragma unroll
        for (int hp = 0; hp < 32; ++hp) {
          unsigned u = wrow[hp];
          acc[2 * hp]     = fmaf(mv, lo16(u), acc[2 * hp]);
          acc[2 * hp + 1] = fmaf(mv, hi16(u), acc[2 * hp + 1]);
        }
      }
      cm[g] = cacc;
#pragma unroll
      for (int u = 0; u < 32; ++u) kp[g][u] = pack2(acc[2 * u], acc[2 * u + 1]);

      for (int rp = 0; rp < 32; ++rp) {
        float a0 = bvl, a1 = bvl;
#pragma unroll
        for (int hq = 0; hq < 32; ++hq) {
          unsigned w = wvt2[hq * 64 + lane];
          float wl = lo16(w), wh = hi16(w);
          const float2 m0 = *(const float2*)&mc[(2 * rp) * 65 + 2 * hq];
          const float2 m1 = *(const float2*)&mc[(2 * rp + 1) * 65 + 2 * hq];
          a0 = fmaf(m0.x, wl, a0); a0 = fmaf(m0.y, wh, a0);
          a1 = fmaf(m1.x, wl, a1); a1 = fmaf(m1.y, wh, a1);
        }
        vt[32 * g + rp] = pack2(a0, a1);
      }
    }
    __syncthreads();
  }

  // ---------------- stage main-phase weights; init dynamic region ----------------
  {
    const float4* s1 = (const float4*)(ws + WS_WPA);   float4* d1 = (float4*)(lds + LD_WPA);
    for (int i = tid; i < 1536; i += 512) d1[i] = s1[i];
    const float4* s2 = (const float4*)(ws + WS_WPB);   float4* d2 = (float4*)(lds + LD_WPB);
    for (int i = tid; i < 1536; i += 512) d2[i] = s2[i];
    const float4* s3 = (const float4*)(ws + WS_G);     float4* d3 = (float4*)(lds + LD_G);
    for (int i = tid; i < 1536; i += 512) d3[i] = s3[i];
    const float4* s4 = (const float4*)(ws + WS_HWT2);  float4* d4 = (float4*)(lds + LD_HWT2);
    for (int i = tid; i < 1024; i += 512) d4[i] = s4[i];
    float* dz = (float*)(lds + LD_DYN);
    for (int i = tid; i < 4 * DYN_STRIDE / 4; i += 512) dz[i] = 0.f;
    if (tid < 5) ((unsigned*)(lds + LD_MISC))[tid] = 0u;  // sBEC[2] u64 + sCONDW
    __syncthreads();
    if (tid < 4) {
      float* se = (float*)(lds + LD_DYN + tid * DYN_STRIDE + DY_SEH);
      se[0] = 1.f; se[1] = 1.f;
    }
    __syncthreads();
  }

  const unsigned* sWPA = (const unsigned*)(lds + LD_WPA);
  const unsigned* sWPB = (const unsigned*)(lds + LD_WPB);
  const unsigned* sG   = (const unsigned*)(lds + LD_G);
  const float2*   sHW2 = (const float2*)(lds + LD_HWT2);
  unsigned char* dynp = lds + LD_DYN + b_local * DYN_STRIDE;
  float* sGI  = (float*)(dynp + DY_GI);
  float* sGH  = (float*)(dynp + DY_GH);
  float* sH0me = (float*)(dynp + (isA ? DY_H0A : DY_H0B));
  float* sH1me = (float*)(dynp + (isA ? DY_H1A : DY_H1B));
  float* sNUM = (float*)(dynp + DY_NUM);
  float* sWE  = (float*)(dynp + (isA ? DY_WEA : DY_WEB));
  float* sSEH = (float*)(dynp + DY_SEH);
  unsigned long long* sBEC = (unsigned long long*)(lds + LD_MISC);
  volatile unsigned* sCONDW = (volatile unsigned*)(lds + LD_MISC + 16);
  unsigned long long* slots = (unsigned long long*)(ws + WS_SLOTS);
  unsigned long long* mirr  = (unsigned long long*)(ws + WS_MIRR);
  const unsigned long long* mline = mirr + (size_t)grp * 8;
  const int* seqb = seq + (size_t)b * LL;

  float h_reg = 0.f;
  float* hsel_last = sH0me;
  // resolver state (live only on block0/wv0); parity-split baselines
  int res_t = 0, rcount = 0;
  unsigned condbits = 0;
  unsigned long long rpe0_0 = 0ull, rpe1_0 = 0ull;   // parity 0 baselines (E0,E1)
  unsigned long long rpe0_1 = 0ull, rpe1_1 = 0ull;   // parity 1 baselines
  bool cprev = false;

  float bh_r = 0.f, bh_z = 0.f, bh_n = 0.f;
  if (!isA) { bh_r = b_hh[lane]; bh_z = b_hh[64 + lane]; bh_n = b_hh[128 + lane]; }
  const float hb_l = head_b[lane];

  float a_gr = 0.f, a_gz = 0.f, a_gn = 0.f, a_dr = 0.f, a_dz = 0.f, a_dn = 0.f;
  float b_hr = 0.f, b_hz = 0.f, b_hn = 0.f;

  for (int t = 0; t < LL; ++t) {
    // ---- phase 1: A computes gi0 + att-delta; B computes gh ----
    if (isA) {
      float Se = sSEH[0] + sSEH[1];
      float rcpSe = 1.0f / Se;
      int token = seqb[t];
      float sr = 0.f, sz = 0.f, sn = 0.f;
#pragma unroll
      for (int q = 0; q < 32; ++q) {
        float2 n0 = *(const float2*)&sNUM[2 * q];
        float2 n1 = *(const float2*)&sNUM[64 + 2 * q];
        float a0 = n0.x + n1.x, a1 = n0.y + n1.y;
        unsigned ur = sWPA[q * 192 + lane];
        unsigned uz = sWPA[q * 192 + 64 + lane];
        unsigned un = sWPA[q * 192 + 128 + lane];
        sr = fmaf(a0, lo16(ur), sr); sr = fmaf(a1, hi16(ur), sr);
        sz = fmaf(a0, lo16(uz), sz); sz = fmaf(a1, hi16(uz), sz);
        sn = fmaf(a0, lo16(un), sn); sn = fmaf(a1, hi16(un), sn);
      }
      unsigned gp0 = sG[token * 96 +      (lane >> 1)];
      unsigned gp1 = sG[token * 96 + 32 + (lane >> 1)];
      unsigned gp2 = sG[token * 96 + 64 + (lane >> 1)];
      bool oddl = (lane & 1);
      a_gr = oddl ? hi16(gp0) : lo16(gp0);
      a_gz = oddl ? hi16(gp1) : lo16(gp1);
      a_gn = oddl ? hi16(gp2) : lo16(gp2);
      a_dr = rcpSe * sr; a_dz = rcpSe * sz; a_dn = rcpSe * sn;
      sGI[lane] = a_gr;        sGI[64 + lane] = a_gz;  sGI[128 + lane] = a_gn;
      sGI[192 + lane] = a_dr;  sGI[256 + lane] = a_dz; sGI[320 + lane] = a_dn;
    } else {
      float hr = bh_r, hz = bh_z, hn = bh_n;
      const float* hprev = hsel_last;   // B's own selected copy from t-1
#pragma unroll
      for (int q = 0; q < 32; ++q) {
        float2 h01 = *(const float2*)&hprev[2 * q];
        unsigned ur = sWPB[q * 192 + lane];
        unsigned uz = sWPB[q * 192 + 64 + lane];
        unsigned un = sWPB[q * 192 + 128 + lane];
        hr = fmaf(h01.x, lo16(ur), hr); hr = fmaf(h01.y, hi16(ur), hr);
        hz = fmaf(h01.x, lo16(uz), hz); hz = fmaf(h01.y, hi16(uz), hz);
        hn = fmaf(h01.x, lo16(un), hn); hn = fmaf(h01.y, hi16(un), hn);
      }
      b_hr = hr; b_hz = hz; b_hn = hn;
      sGH[lane] = hr; sGH[64 + lane] = hz; sGH[128 + lane] = hn;
    }
    __syncthreads();   // X

    // ---- phase 2: both-branch gates (redundant & bit-identical on A and B) ----
    float gi_r, gi_z, gi_n, da_r, da_z, da_n, gh_r, gh_z, gh_n;
    if (isA) {
      gh_r = sGH[lane]; gh_z = sGH[64 + lane]; gh_n = sGH[128 + lane];
      gi_r = a_gr; gi_z = a_gz; gi_n = a_gn; da_r = a_dr; da_z = a_dz; da_n = a_dn;
    } else {
      gi_r = sGI[lane];       gi_z = sGI[64 + lane];  gi_n = sGI[128 + lane];
      da_r = sGI[192 + lane]; da_z = sGI[256 + lane]; da_n = sGI[320 + lane];
      gh_r = b_hr; gh_z = b_hz; gh_n = b_hn;
    }
    float xr0 = gi_r + gh_r, xz0 = gi_z + gh_z;
    float rg0 = 1.f / (1.f + __expf(-xr0));
    float rg1 = 1.f / (1.f + __expf(-(xr0 + da_r)));
    float zg0 = 1.f / (1.f + __expf(-xz0));
    float zg1 = 1.f / (1.f + __expf(-(xz0 + da_z)));
    float na0 = fmaf(rg0, gh_n, gi_n);
    float na1 = fmaf(rg1, gh_n, gi_n + da_n);
    float ee0 = __expf(-2.f * na0), ee1 = __expf(-2.f * na1);
    float n0 = (1.f - ee0) / (1.f + ee0);
    float n1 = (1.f - ee1) / (1.f + ee1);
    float h0 = (1.f - zg0) * n0 + zg0 * h_reg;
    float h1 = (1.f - zg1) * n1 + zg1 * h_reg;
    sH0me[lane] = h0; sH1me[lane] = h1;
    WAVE_FENCE();

    // ---- phase 3: entropy on own branch (A:h0, B:h1) -> LDS combine -> far post ----
    {
      const float* hme = isA ? sH0me : sH1me;
      float lo = hb_l;
#pragma unroll
      for (int hp = 0; hp < 32; ++hp) {
        float2 h01 = *(const float2*)&hme[2 * hp];
        float2 w = sHW2[hp * 64 + lane];
        lo = fmaf(h01.x, w.x, lo); lo = fmaf(h01.y, w.y, lo);
      }
      float pu = __expf(lo);
      float Ss = pu;
#pragma unroll
      for (int off = 32; off; off >>= 1) Ss += __shfl_xor(Ss, off, 64);
      float pr = pu / Ss;
      float ent = pr * __logf(pr + 1e-8f);
#pragma unroll
      for (int off = 32; off; off >>= 1) ent += __shfl_xor(ent, off, 64);
      if (lane == 0) {
        float be = fmaxf(-ent, 0.f);
        unsigned long long fp = (unsigned long long)(unsigned)(be * 1048576.0f + 0.5f);
        unsigned long long add = (1ull << 60) | (isA ? fp : (fp << 30));
        unsigned long long old = atomicAdd(&sBEC[t & 1], add);
        if ((old >> 60) == 7ull) {   // 8th arrival: publish both branch sums
          unsigned long long tot = old + add;
          unsigned long long e0s = tot & M30;
          unsigned long long e1s = (tot >> 30) & M30;
          unsigned long long* line = slots + ((size_t)grp * 2 + (size_t)(t & 1)) * 8;
          __hip_atomic_fetch_add(line,     (1ull << 48) | e0s,
                                 __ATOMIC_RELAXED, __HIP_MEMORY_SCOPE_AGENT);
          __hip_atomic_fetch_add(line + 1, (1ull << 48) | e1s,
                                 __ATOMIC_RELAXED, __HIP_MEMORY_SCOPE_AGENT);
          sBEC[t & 1] = 0ull;
        }
      }
    }

    // ---- phase 4: resolve cond(t-1) ----
    bool condp = false;
    if (t > 0) {
      if (isRes) {
        while (res_t < t) {
          int par = res_t & 1;
          unsigned long long* lp = slots + ((size_t)lane * 2 + (size_t)par) * 8;
          unsigned long long b0 = par ? rpe0_1 : rpe0_0;
          unsigned long long b1 = par ? rpe1_1 : rpe1_0;
          unsigned long long c0, c1;
          int guard = SPIN_FAR;
          for (;;) {
            c0 = __hip_atomic_load(lp,     __ATOMIC_RELAXED, __HIP_MEMORY_SCOPE_AGENT);
            c1 = __hip_atomic_load(lp + 1, __ATOMIC_RELAXED, __HIP_MEMORY_SCOPE_AGENT);
            bool ok = (((c0 - b0) >> 48) == 4ull) && (((c1 - b1) >> 48) == 4ull);
            if (__all(ok)) break;
            if (--guard <= 0) break;     // safety escape (visible as wrong output)
            __builtin_amdgcn_s_sleep(1);
          }
          unsigned long long d = cprev ? ((c1 - b1) & M48) : ((c0 - b0) & M48);
          if (par) { rpe0_1 = c0; rpe1_1 = c1; } else { rpe0_0 = c0; rpe1_0 = c1; }
#pragma unroll
          for (int off = 32; off; off >>= 1) d += __shfl_xor(d, off, 64);
          bool c = d > GATE_SUM;
          cprev = c; rcount += c ? 1 : 0;
          condbits = (condbits << 1) | (c ? 1u : 0u);
          ++res_t;
          unsigned long long mv = ((unsigned long long)res_t << 32) | condbits;
          __hip_atomic_store(mirr + (size_t)lane * 8, mv,
                             __ATOMIC_RELAXED, __HIP_MEMORY_SCOPE_AGENT);
        }
        condp = cprev;
        if (lane == 0) *sCONDW = ((unsigned)(t + 1) << 1) | (condp ? 1u : 0u);
      } else if (wv == 0) {
        unsigned long long v;
        unsigned hi;
        int guard = SPIN_FAR;
        for (;;) {
          v = __hip_atomic_load(mline, __ATOMIC_RELAXED, __HIP_MEMORY_SCOPE_AGENT);
          hi = (unsigned)(v >> 32);
          if (hi >= (unsigned)t) break;
          if (--guard <= 0) break;
          __builtin_amdgcn_s_sleep(1);
        }
        condp = (hi >= (unsigned)t) ? (((v >> (hi - (unsigned)t)) & 1ull) != 0ull) : false;
        if (lane == 0) *sCONDW = ((unsigned)(t + 1) << 1) | (condp ? 1u : 0u);
      } else {
        unsigned cv;
        int guard = SPIN_LDS;
        for (;;) {
          cv = *sCONDW;
          if ((cv >> 1) == (unsigned)(t + 1)) break;
          if (--guard <= 0) break;
          __builtin_amdgcn_s_sleep(0);
        }
        condp = ((cv >> 1) == (unsigned)(t + 1)) ? ((cv & 1u) != 0u) : false;
      }
    }
    float h_new = condp ? h1 : h0;
    float* hsel = condp ? sH1me : sH0me;
    hsel_last = hsel;
    h_reg = h_new;

    // ---- phase 5: attention on selected h (own half; no max-sub, bounded) ----
    float s0 = cm[0], s1 = cm[1];
#pragma unroll
    for (int hp = 0; hp < 32; ++hp) {
      float2 h01 = *(const float2*)&hsel[2 * hp];
      unsigned u0 = kp[0][hp], u1 = kp[1][hp];
      s0 = fmaf(h01.x, lo16(u0), s0); s0 = fmaf(h01.y, hi16(u0), s0);
      s1 = fmaf(h01.x, lo16(u1), s1); s1 = fmaf(h01.y, hi16(u1), s1);
    }
    float e0 = __expf(s0 * SCALE_), e1 = __expf(s1 * SCALE_);
    float seh = e0 + e1;
#pragma unroll
    for (int off = 32; off; off >>= 1) seh += __shfl_xor(seh, off, 64);
    sWE[lane] = e0; sWE[64 + lane] = e1;
    if (lane == 0) sSEH[half] = seh;
    WAVE_FENCE();

    float al = 0.f;
    const float4* w4 = (const float4*)sWE;
#pragma unroll
    for (int mp = 0; mp < 32; ++mp) {
      float4 wq4 = w4[mp];
      unsigned u0 = vt[2 * mp], u1 = vt[2 * mp + 1];
      al = fmaf(wq4.x, lo16(u0), al);
      al = fmaf(wq4.y, hi16(u0), al);
      al = fmaf(wq4.z, lo16(u1), al);
      al = fmaf(wq4.w, hi16(u1), al);
    }
    sNUM[half * 64 + lane] = al;
    __syncthreads();   // W: num/Se published for next step
  }

  // ---- resolver finishes the last step (read_rate only) ----
  if (isRes) {
    while (res_t < LL) {
      int par = res_t & 1;
      unsigned long long* lp = slots + ((size_t)lane * 2 + (size_t)par) * 8;
      unsigned long long b0 = par ? rpe0_1 : rpe0_0;
      unsigned long long b1 = par ? rpe1_1 : rpe1_0;
      unsigned long long c0, c1;
      int guard = SPIN_FAR;
      for (;;) {
        c0 = __hip_atomic_load(lp,     __ATOMIC_RELAXED, __HIP_MEMORY_SCOPE_AGENT);
        c1 = __hip_atomic_load(lp + 1, __ATOMIC_RELAXED, __HIP_MEMORY_SCOPE_AGENT);
        bool ok = (((c0 - b0) >> 48) == 4ull) && (((c1 - b1) >> 48) == 4ull);
        if (__all(ok)) break;
        if (--guard <= 0) break;
        __builtin_amdgcn_s_sleep(1);
      }
      unsigned long long d = cprev ? ((c1 - b1) & M48) : ((c0 - b0) & M48);
      if (par) { rpe0_1 = c0; rpe1_1 = c1; } else { rpe0_0 = c0; rpe1_0 = c1; }
#pragma unroll
      for (int off = 32; off; off >>= 1) d += __shfl_xor(d, off, 64);
      bool c = d > GATE_SUM;
      cprev = c; rcount += c ? 1 : 0;
      ++res_t;
    }
    if (lane == 0) out[BB * 64] = (float)rcount / (float)LL;
  }

  // ---- final logits with f32 head weights (from selected h copy) ----
  if (isA) {
    float lof = hb_l;
#pragma unroll 8
    for (int h = 0; h < 64; ++h) lof = fmaf(hsel_last[h], head_w[lane * 64 + h], lof);
    out[(size_t)b * 64 + lane] = lof;
  }
}

// =====================================================================
extern "C" void kernel_launch(void* const* d_in, const int* in_sizes, int n_in,
                              void* d_out, int out_size, void* d_ws, size_t ws_size,
                              hipStream_t stream)
{
  (void)in_sizes; (void)n_in; (void)out_size; (void)ws_size;
  const int*   seq    = (const int*)  d_in[0];
  const float* memory = (const float*)d_in[1];
  const float* embed  = (const float*)d_in[2];
  const float* w_ih   = (const float*)d_in[3];
  const float* w_hh   = (const float*)d_in[4];
  const float* b_ih   = (const float*)d_in[5];
  const float* b_hh   = (const float*)d_in[6];
  const float* wq     = (const float*)d_in[7];
  const float* bq     = (const float*)d_in[8];
  const float* wk     = (const float*)d_in[9];
  const float* bk     = (const float*)d_in[10];
  const float* wv     = (const float*)d_in[11];
  const float* bv     = (const float*)d_in[12];
  const float* head_w = (const float*)d_in[13];
  const float* head_b = (const float*)d_in[14];
  unsigned char* ws   = (unsigned char*)d_ws;
  float* out          = (float*)d_out;

  // zero cumulative slots + mirror every call (graph-safe)
  hipMemsetAsync(d_ws, 0, 12288, stream);

  hipLaunchKernelGGL(reactive_pre, dim3(1), dim3(1024), 0, stream,
                     embed, w_ih, w_hh, b_ih, wq, bq, wk, bk, head_w, ws);

  hipFuncSetAttribute((const void*)reactive_main,
                      hipFuncAttributeMaxDynamicSharedMemorySize, LDS_BYTES);
  hipLaunchKernelGGL(reactive_main, dim3(256), dim3(512), LDS_BYTES, stream,
                     seq, memory, wv, bv, b_hh, head_w, head_b, ws, out);
}